// Round 12
// baseline (260.153 us; speedup 1.0000x reference)
//
#include <hip/hip_runtime.h>
#include <math.h>

// NAMClassifier: B=16384 rows, F=256 independent 1->64->32->1 MLPs.
// R12: (a) x-transpose eliminated — main reads x directly via float4
// (lane = row; 16 feature-loads/lane hit one 64B line) + shfl broadcast;
// prep is now just the 256-block weight pack (~3us vs ~17us).
// (b) occupancy 4->6 waves/SIMD: FPW 16->8, grid 1024 x 512thr,
// launch_bounds(512,6). Plain-store partials (no atomics), tiny merge.

#define NAM_B 16384
#define NAM_F 256
#define FPW   8                // features per wave
#define NFS   (NAM_F / FPW)    // 32 feature splits
#define RPW   64               // rows per wave
#define WPB   8                // waves per block (512 threads)
#define NBLK  ((NAM_B / RPW) * NFS / WPB)   // 1024 blocks

typedef __attribute__((ext_vector_type(8))) _Float16 f16x8;
typedef __attribute__((ext_vector_type(2))) _Float16 f16x2;
typedef __attribute__((ext_vector_type(4))) float    f32x4;

union pk8 { f16x8 v; f16x2 h[4]; };

// ---- prep: one block per feature — w2p A-frags + w1p/b1p f16 pairs ----
__global__ __launch_bounds__(256) void nam_prep(
    const float* __restrict__ W2, const float* __restrict__ W1,
    const float* __restrict__ b1,
    _Float16* __restrict__ w2p, _Float16* __restrict__ w1p,
    _Float16* __restrict__ b1p) {
    const int f = blockIdx.x;
    const int t = threadIdx.x;
    // W2[f][64][32] -> A-fragments [f*4 + s*2 + a][64 lanes][8]
    // elem j of lane L: W2[f][s*32 + (L>>4)*8 + j][a*16 + (L&15)]
    const int s = t >> 7, a = (t >> 6) & 1, L = t & 63;
    const int hi = L >> 4, m = L & 15;
    const float* __restrict__ W2f = W2 + (size_t)f * (64*32);
    f16x8 o;
    #pragma unroll
    for (int j = 0; j < 8; ++j)
        o[j] = (_Float16)W2f[(s*32 + hi*8 + j)*32 + a*16 + m];
    *reinterpret_cast<f16x8*>(w2p + ((size_t)(f*4 + s*2 + a)*64 + L) * 8) = o;
    // w1p/b1p: index [(f*2+s)*4+hi], elems j = src[f*64 + s*32 + hi*8 + j]
    if (t < 16) {
        const int which = t >> 3;          // 0: W1, 1: b1
        const int s2 = (t >> 2) & 1, hi2 = t & 3;
        const float* __restrict__ src = (which ? b1 : W1) + f*64 + s2*32 + hi2*8;
        f16x8 o2;
        #pragma unroll
        for (int j = 0; j < 8; ++j) o2[j] = (_Float16)src[j];
        _Float16* dst = (which ? b1p : w1p) + ((size_t)(f*2 + s2)*4 + hi2)*8;
        *reinterpret_cast<f16x8*>(dst) = o2;
    }
}

// ---- main: wave = 64 rows x 8 features; direct x reads; plain stores ----
__global__ __launch_bounds__(512, 6) void nam_main(
    const float* __restrict__ x,  const float* __restrict__ b2,
    const float* __restrict__ W3, const float* __restrict__ b3,
    const _Float16* __restrict__ w2p, const _Float16* __restrict__ w1p,
    const _Float16* __restrict__ b1p,
    float* __restrict__ partial) {   // [NFS][NAM_B]
    const int t = threadIdx.x;
    const int w = t >> 6, lane = t & 63;
    const int hi = lane >> 4, m = lane & 15;
    const int fs = blockIdx.x >> 5;                       // 0..31
    const int r0 = ((blockIdx.x & 31) * WPB + w) * RPW;   // row base
    const int fbase = fs * FPW;

    const f16x8* __restrict__ wp8 = reinterpret_cast<const f16x8*>(w2p);
    const f16x2 hzero = {(_Float16)0.f, (_Float16)0.f};

    // this lane's row slice of x: 8 features = 32B, within one 64B line
    const float* __restrict__ xrow = x + (size_t)(r0 + lane) * NAM_F + fbase;
    const float4 xq0 = *reinterpret_cast<const float4*>(xrow);
    const float4 xq1 = *reinterpret_cast<const float4*>(xrow + 4);

    float rs[4] = {0.f, 0.f, 0.f, 0.f};
    float b3sum = 0.f;

    #pragma unroll
    for (int i = 0; i < FPW; ++i) {          // full unroll: static float4 comps
        const int f = fbase + i;
        const f16x8 a00 = wp8[(size_t)(f*4 + 0)*64 + lane];
        const f16x8 a01 = wp8[(size_t)(f*4 + 1)*64 + lane];
        const f16x8 a10 = wp8[(size_t)(f*4 + 2)*64 + lane];
        const f16x8 a11 = wp8[(size_t)(f*4 + 3)*64 + lane];
        pk8 w10, w11, b10, b11;
        w10.v = *reinterpret_cast<const f16x8*>(w1p + ((size_t)(f*2+0)*4 + hi)*8);
        w11.v = *reinterpret_cast<const f16x8*>(w1p + ((size_t)(f*2+1)*4 + hi)*8);
        b10.v = *reinterpret_cast<const f16x8*>(b1p + ((size_t)(f*2+0)*4 + hi)*8);
        b11.v = *reinterpret_cast<const f16x8*>(b1p + ((size_t)(f*2+1)*4 + hi)*8);
        const f32x4 b2v0 = *reinterpret_cast<const f32x4*>(b2 + f*32 + hi*4);
        const f32x4 b2v1 = *reinterpret_cast<const f32x4*>(b2 + f*32 + 16 + hi*4);
        const f32x4 w3v0 = *reinterpret_cast<const f32x4*>(W3 + f*32 + hi*4);
        const f32x4 w3v1 = *reinterpret_cast<const f32x4*>(W3 + f*32 + 16 + hi*4);
        b3sum += b3[f];
        const float xf_mine = (i < 4) ? ((i & 3) == 0 ? xq0.x : (i & 3) == 1 ? xq0.y
                                       : (i & 3) == 2 ? xq0.z : xq0.w)
                                      : ((i & 3) == 0 ? xq1.x : (i & 3) == 1 ? xq1.y
                                       : (i & 3) == 2 ? xq1.z : xq1.w);

        #pragma unroll
        for (int sub = 0; sub < 4; ++sub) {
            // broadcast x[row r0+sub*16+m][f] from lane sub*16+m
            const float xf = __shfl(xf_mine, sub*16 + m);
            const _Float16 xh = (_Float16)xf;
            const f16x2 xb = {xh, xh};
            pk8 bf0, bf1;
            #pragma unroll
            for (int u = 0; u < 4; ++u) {
                bf0.h[u] = __builtin_elementwise_max(xb * w10.h[u] + b10.h[u], hzero);
                bf1.h[u] = __builtin_elementwise_max(xb * w11.h[u] + b11.h[u], hzero);
            }
            f32x4 acc0 = __builtin_amdgcn_mfma_f32_16x16x32_f16(a00, bf0.v, b2v0, 0,0,0);
            acc0       = __builtin_amdgcn_mfma_f32_16x16x32_f16(a10, bf1.v, acc0, 0,0,0);
            f32x4 acc1 = __builtin_amdgcn_mfma_f32_16x16x32_f16(a01, bf0.v, b2v1, 0,0,0);
            acc1       = __builtin_amdgcn_mfma_f32_16x16x32_f16(a11, bf1.v, acc1, 0,0,0);
            float ts = 0.f;
            #pragma unroll
            for (int r = 0; r < 4; ++r) {
                ts = fmaf(fmaxf(acc0[r], 0.f), w3v0[r], ts);
                ts = fmaf(fmaxf(acc1[r], 0.f), w3v1[r], ts);
            }
            ts += __shfl_xor(ts, 16);   // reduce over h2 blocks
            ts += __shfl_xor(ts, 32);
            rs[sub] += ts;
        }
    }

    // lane L stores row r0+L -> one coalesced 256B store per wave
    float vsel = (lane < 16) ? rs[0] : (lane < 32) ? rs[1]
               : (lane < 48) ? rs[2] : rs[3];
    partial[(size_t)fs * NAM_B + r0 + lane] = vsel + b3sum;
}

// ---- merge: bias + sum 32 splits + sigmoid ----
__global__ __launch_bounds__(256) void nam_merge(
    const float* __restrict__ partial, const float* __restrict__ bias,
    float* __restrict__ out) {
    const int r = blockIdx.x * 256 + threadIdx.x;
    float s = bias[0];
    #pragma unroll
    for (int g = 0; g < NFS; ++g) s += partial[(size_t)g * NAM_B + r];
    out[r] = s;
    out[NAM_B + r] = 1.0f / (1.0f + expf(-s));
}

extern "C" void kernel_launch(void* const* d_in, const int* in_sizes, int n_in,
                              void* d_out, int out_size, void* d_ws, size_t ws_size,
                              hipStream_t stream) {
    const float* x    = (const float*)d_in[0];
    const float* W1   = (const float*)d_in[1];
    const float* b1   = (const float*)d_in[2];
    const float* W2   = (const float*)d_in[3];
    const float* b2   = (const float*)d_in[4];
    const float* W3   = (const float*)d_in[5];
    const float* b3   = (const float*)d_in[6];
    const float* bias = (const float*)d_in[7];
    float* out = (float*)d_out;

    // ws: w2p 1MB | w1p 32KB | b1p 32KB | partial [32][16384] f32 2MB
    _Float16* w2p = (_Float16*)d_ws;
    _Float16* w1p = w2p + (size_t)NAM_F * 64 * 32;
    _Float16* b1p = w1p + (size_t)NAM_F * 64;
    float* partial = (float*)(b1p + (size_t)NAM_F * 64);

    nam_prep<<<dim3(NAM_F), 256, 0, stream>>>(W2, W1, b1, w2p, w1p, b1p);
    nam_main<<<dim3(NBLK), 512, 0, stream>>>(x, b2, W3, b3, w2p, w1p, b1p, partial);
    nam_merge<<<dim3(NAM_B / 256), 256, 0, stream>>>(partial, bias, out);
}